// Round 13
// baseline (419.556 us; speedup 1.0000x reference)
//
#include <hip/hip_runtime.h>
#include <hip/hip_bf16.h>

// Problem constants (ResNet-50 CBP head)
#define BATCH 8
#define CH    2048
#define LSP   784          // H*W = 28*28
#define KPAD  800          // pad K to 25*32 for MFMA k-steps
#define KSTEPS (KPAD/32)   // 25
#define DDIM  8192         // count-sketch dim (power of 2)
#define NCLS  200
#define NTILE 16           // 2048/128 tiles per dim
#define NPAIR 136          // NTILE*(NTILE+1)/2 symmetric tile pairs
#define NSLOT 136          // one part slot per pair -> nt-store flush

typedef _Float16 f16x8 __attribute__((ext_vector_type(8)));
typedef _Float16 f16x4 __attribute__((ext_vector_type(4)));
typedef float    f32x4 __attribute__((ext_vector_type(4)));

#define FATOMIC(p, v) unsafeAtomicAdd((p), (v))

// ---------------------------------------------------------------------------
// Kernel 1: convert x (fp32 [B,C,784]) to fp16 [B,C,KPAD] (zero-pad K).
// Zero norm/done and the logit area of out (harness poisons with 0xAA).
// ---------------------------------------------------------------------------
__global__ __launch_bounds__(256) void split_kernel(
    const float* __restrict__ x,
    _Float16* __restrict__ xh,
    float* __restrict__ norm, int* __restrict__ done,
    float* __restrict__ out)
{
    int idx = blockIdx.x * 256 + threadIdx.x;          // vec4 index
    if (idx < BATCH) norm[idx] = 0.0f;
    if (idx == BATCH) *done = 0;
    if (idx < BATCH * NCLS) out[idx] = 0.0f;           // logit_u accumulator
    if (idx >= BATCH * CH * KPAD / 4) return;
    int v  = idx * 4;
    int bc_ = v / KPAD;
    int l  = v - bc_ * KPAD;                           // multiple of 4
    float4 xv = make_float4(0.f, 0.f, 0.f, 0.f);
    if (l < LSP)                                       // LSP%4==0: uniform per vec
        xv = *(const float4*)&x[(size_t)bc_ * LSP + l];
    f16x4 hv;
    hv[0] = (_Float16)xv.x; hv[1] = (_Float16)xv.y;
    hv[2] = (_Float16)xv.z; hv[3] = (_Float16)xv.w;
    *(f16x4*)&xh[v] = hv;
}

// ---------------------------------------------------------------------------
// Kernel 2: symmetric Gram tile (fp16 MFMA) + LDS count-sketch scatter.
// grid = 1088: batch = id&7 (one batch per XCD), pair = id>>3.
// Scatter roofline: ds_add_f32 RMW throughput ~2.9 cyc/lane-op (measured).
// Flush = NON-TEMPORAL f32x4 stores to the pair's private part slot:
// keeps the streaming 35.7 MB out of L2 so the xh working set stays
// resident (R11: regular stores evicted it, FETCH 13->18.7 MB, +18 us).
// ---------------------------------------------------------------------------
__device__ __forceinline__ void stage_tile(
    const _Float16* __restrict__ src, size_t rowbase_elems,
    unsigned short* lds_tile, int wv, int lane, int k0)
{
#pragma unroll
    for (int half = 0; half < 2; ++half) {
        int ch  = wv * 2 + half;                       // 0..7 chunk of 8KB tile
        int row = ch * 16 + (lane >> 2);
        int kg  = (lane & 3) ^ ((lane >> 3) & 3);      // XOR swizzle (row>>1)&3
        const _Float16* g = src + rowbase_elems
            + (size_t)row * KPAD + k0 + kg * 8;
        __builtin_amdgcn_global_load_lds(
            (__attribute__((address_space(1))) void*)g,
            (__attribute__((address_space(3))) void*)(lds_tile + ch * 512),
            16, 0, 0);
    }
}

__global__ __launch_bounds__(256, 3) void gram_scatter_kernel(
    const _Float16* __restrict__ xh,
    const int*   __restrict__ h1, const float* __restrict__ s1,
    const int*   __restrict__ h2, const float* __restrict__ s2,
    float* __restrict__ part)
{
    __shared__ __align__(16) unsigned short smA[128 * 32];   // 8 KB fp16 tile
    __shared__ __align__(16) unsigned short smB[128 * 32];   // 8 KB
    __shared__ __align__(16) float bins[DDIM];               // 32 KB
    __shared__ float4 metaA[128];                            // 2 KB

    const int tid  = threadIdx.x;
    const int lane = tid & 63;
    const int wv   = tid >> 6;
    const int b    = blockIdx.x & 7;       // batch in low bits -> one batch/XCD
    const int pidx = blockIdx.x >> 3;      // triangular pair index

    // Triangular decode: pidx in [0,136) -> (tM, tN), tM <= tN, row-major
    int tM = 0, tN = 0;
    {
        int i = pidx;
#pragma unroll 1
        for (int t = 0; t < NTILE; ++t) {
            int cnt = NTILE - t;
            if (i < cnt) { tM = t; tN = t + i; break; }
            i -= cnt;
        }
    }
    const bool diag = (tM == tN);

    for (int i = tid; i < DDIM; i += 256) bins[i] = 0.0f;
    // (first __syncthreads inside k-loop orders this before any scatter)

    const int wrow = (wv >> 1) * 64;    // wave's 64x64 subtile origin
    const int wcol = (wv & 1) * 64;

    const size_t rowbaseA = ((size_t)b * CH + (size_t)tM * 128) * KPAD;
    const size_t rowbaseB = ((size_t)b * CH + (size_t)tN * 128) * KPAD;

    const unsigned short* fragB = diag ? smA : smB;

    f32x4 acc[4][4];
    const f32x4 zv = {0.0f, 0.0f, 0.0f, 0.0f};
#pragma unroll
    for (int mi = 0; mi < 4; ++mi)
#pragma unroll
        for (int ni = 0; ni < 4; ++ni) acc[mi][ni] = zv;

    // fragment LDS offset: (row)*32 + fxor; XOR term is a per-lane constant
    const int fxor = (((lane >> 4) ^ ((lane >> 1) & 3)) << 3);
    const int rsel = lane & 15;

    for (int ks = 0; ks < KSTEPS; ++ks) {
        const int k0 = ks * 32;
        stage_tile(xh, rowbaseA, smA, wv, lane, k0);
        if (!diag) stage_tile(xh, rowbaseB, smB, wv, lane, k0);
        __syncthreads();

        f16x8 ah[4], bh[4];
#pragma unroll
        for (int i = 0; i < 4; ++i) {
            int offa = (wrow + i * 16 + rsel) * 32 + fxor;
            ah[i] = *(const f16x8*)&smA[offa];
            int offb = (wcol + i * 16 + rsel) * 32 + fxor;
            bh[i] = *(const f16x8*)&fragB[offb];
        }
#pragma unroll
        for (int mi = 0; mi < 4; ++mi)
#pragma unroll
            for (int ni = 0; ni < 4; ++ni)
                acc[mi][ni] = __builtin_amdgcn_mfma_f32_16x16x32_f16(ah[mi], bh[ni], acc[mi][ni], 0, 0, 0);
        __syncthreads();
    }

    // Stage scatter meta for this tile's 128 c1-rows into LDS.
    if (tid < 128) {
        int c1 = tM * 128 + tid;
        metaA[tid] = make_float4(s1[c1], __int_as_float(h1[c1]),
                                 s2[c1], __int_as_float(h2[c1]));
    }
    __syncthreads();

    // Scatter the 128x128 Gram tile into the LDS histogram.
    // C/D layout (m89-verified): col = lane&15, row = (lane>>4)*4 + reg
    // Off-diagonal pair: each entry contributes twice (G symmetric).
    const int c2b = tN * 128 + wcol + (lane & 15);
    const int rowsel = wrow + ((lane >> 4) << 2);
    int   h1c[4], h2c[4]; float s1c[4], s2c[4];
#pragma unroll
    for (int ni = 0; ni < 4; ++ni) {
        int c2 = c2b + ni * 16;
        h1c[ni] = h1[c2]; s1c[ni] = s1[c2];
        h2c[ni] = h2[c2]; s2c[ni] = s2[c2];
    }
#pragma unroll
    for (int mi = 0; mi < 4; ++mi) {
#pragma unroll
        for (int r = 0; r < 4; ++r) {
            float4 m = metaA[rowsel + mi * 16 + r];    // one ds_read_b128
            const float s1r = m.x, s2r = m.z;
            const int h1r = __float_as_int(m.y);
            const int h2r = __float_as_int(m.w);
#pragma unroll
            for (int ni = 0; ni < 4; ++ni) {
                float g = acc[mi][ni][r];
                FATOMIC(&bins[(h1r + h2c[ni]) & (DDIM - 1)], s1r * s2c[ni] * g);
                if (!diag)
                    FATOMIC(&bins[(h1c[ni] + h2r) & (DDIM - 1)], s1c[ni] * s2r * g);
            }
        }
    }

    __syncthreads();   // all scatters into bins complete

    // Non-temporal store-flush (ext_vector f32x4 — the builtin accepts
    // Clang vector types, not HIP's float4 class).
    f32x4* pb4 = (f32x4*)(part + ((size_t)(pidx * BATCH + b) * DDIM));
    const f32x4* bins4 = (const f32x4*)bins;
    for (int i = tid; i < DDIM / 4; i += 256)
        __builtin_nontemporal_store(bins4[i], &pb4[i]);
}

// ---------------------------------------------------------------------------
// Kernel 3 (fused head): per d-slice, sum 136 part slots -> y, signed-sqrt
// -> unnormalized feat (stored), accumulate norm[b] and unnormalized logits
// (logit = (featU @ W)/||featU|| + b applied at the end).  The LAST block
// (fence + ticket) rescales feat and logits in place.
// grid 64: block j owns d in [128j, 128j+128) for all batches.
// ---------------------------------------------------------------------------
__global__ __launch_bounds__(256) void head_kernel(
    const float* __restrict__ part, const float* __restrict__ W,
    const float* __restrict__ bc, float* __restrict__ out,
    float* __restrict__ norm, int* __restrict__ done)
{
    const int j = blockIdx.x;
    const int tid = threadIdx.x;
    __shared__ float fs[BATCH][128];                   // 4 KB
    __shared__ float nloc[BATCH];
    __shared__ int ticket;
    if (tid < BATCH) nloc[tid] = 0.0f;
    __syncthreads();

    for (int i = tid; i < BATCH * 128; i += 256) {
        int b = i >> 7, dd = i & 127;
        int d = j * 128 + dd;
        float s = 0.0f;
#pragma unroll 8
        for (int p = 0; p < NSLOT; ++p)
            s += part[((size_t)(p * BATCH + b)) * DDIM + d];
        float fu = copysignf(sqrtf(fabsf(s)), s);
        fs[b][dd] = fu;
        out[BATCH * NCLS + (size_t)b * DDIM + d] = fu; // unnormalized feat
        FATOMIC(&nloc[b], fabsf(s));                   // sum|y| == sum featU^2
    }
    __syncthreads();
    if (tid < BATCH) FATOMIC(&norm[tid], nloc[tid]);

    if (tid < NCLS) {
        float a[BATCH];
#pragma unroll
        for (int bb = 0; bb < BATCH; ++bb) a[bb] = 0.0f;
        for (int dd = 0; dd < 128; ++dd) {
            float w = W[(size_t)(j * 128 + dd) * NCLS + tid];
#pragma unroll
            for (int bb = 0; bb < BATCH; ++bb) a[bb] += fs[bb][dd] * w;
        }
#pragma unroll
        for (int bb = 0; bb < BATCH; ++bb)
            FATOMIC(&out[bb * NCLS + tid], a[bb]);     // logit_u (zero-seeded)
    }

    // --- last-block rescale ---
    __threadfence();
    __syncthreads();
    if (tid == 0) ticket = atomicAdd(done, 1);
    __syncthreads();
    if (ticket == 63) {
        __threadfence();
        __shared__ float inv[BATCH];
        if (tid < BATCH) inv[tid] = 1.0f / fmaxf(sqrtf(norm[tid]), 1e-12f);
        __syncthreads();
        for (int i = tid; i < BATCH * DDIM; i += 256) {
            int b = i >> 13;                           // i / DDIM
            out[BATCH * NCLS + i] *= inv[b];
        }
        for (int i = tid; i < BATCH * NCLS; i += 256) {
            int b = i / NCLS, n = i - b * NCLS;
            out[i] = out[i] * inv[b] + bc[n];
        }
    }
}

// ---------------------------------------------------------------------------
extern "C" void kernel_launch(void* const* d_in, const int* in_sizes, int n_in,
                              void* d_out, int out_size, void* d_ws, size_t ws_size,
                              hipStream_t stream)
{
    const float* x  = (const float*)d_in[0];
    const float* s1 = (const float*)d_in[1];
    const float* s2 = (const float*)d_in[2];
    const float* W  = (const float*)d_in[3];
    const float* bc = (const float*)d_in[4];
    const int*   h1 = (const int*)d_in[5];
    const int*   h2 = (const int*)d_in[6];
    float* out = (float*)d_out;

    // ws layout: part (35.7MB) | norm (128B) | done (128B) | xh (26.2MB)
    char* ws = (char*)d_ws;
    float* part = (float*)ws;
    const size_t partbytes = (size_t)NSLOT * BATCH * DDIM * sizeof(float);
    float* norm = (float*)(ws + partbytes);
    int*   done = (int*)(ws + partbytes + 128);
    _Float16* xh = (_Float16*)(ws + partbytes + 256);

    split_kernel<<<(BATCH * CH * KPAD / 4 + 255) / 256, 256, 0, stream>>>(
        x, xh, norm, done, out);

    gram_scatter_kernel<<<NPAIR * BATCH, 256, 0, stream>>>(
        xh, h1, s1, h2, s2, part);

    head_kernel<<<64, 256, 0, stream>>>(part, W, bc, out, norm, done);
}

// Round 14
// 408.819 us; speedup vs baseline: 1.0263x; 1.0263x over previous
//
#include <hip/hip_runtime.h>
#include <hip/hip_bf16.h>

// Problem constants (ResNet-50 CBP head)
#define BATCH 8
#define CH    2048
#define LSP   784          // H*W = 28*28
#define KPAD  800          // pad K to 25*32 for MFMA k-steps
#define KSTEPS (KPAD/32)   // 25
#define DDIM  8192         // count-sketch dim (power of 2)
#define NCLS  200
#define NTILE 16           // 2048/128 tiles per dim
#define NPAIR 136          // NTILE*(NTILE+1)/2 symmetric tile pairs
#define NSLOT 68           // part slots per batch (2 blocks/slot, atomic flush)

typedef _Float16 f16x8 __attribute__((ext_vector_type(8)));
typedef _Float16 f16x4 __attribute__((ext_vector_type(4)));
typedef float    f32x4 __attribute__((ext_vector_type(4)));

#define FATOMIC(p, v) unsafeAtomicAdd((p), (v))

// ---------------------------------------------------------------------------
// Kernel 1: convert x (fp32 [B,C,784]) to fp16 [B,C,KPAD] (zero-pad K).
// Zero part (vec4) / norm / done; zero the logit accumulator area of out.
// ---------------------------------------------------------------------------
__global__ __launch_bounds__(256) void split_kernel(
    const float* __restrict__ x,
    _Float16* __restrict__ xh,
    float* __restrict__ part, float* __restrict__ norm,
    int* __restrict__ done, float* __restrict__ out)
{
    int idx = blockIdx.x * 256 + threadIdx.x;          // vec4 index
    if (idx < NSLOT * BATCH * DDIM / 4)                // zero part (float4)
        *(float4*)&part[idx * 4] = make_float4(0.f, 0.f, 0.f, 0.f);
    if (idx < BATCH) norm[idx] = 0.0f;
    if (idx == BATCH) *done = 0;
    if (idx < BATCH * NCLS) out[idx] = 0.0f;           // logit_u accumulator
    if (idx >= BATCH * CH * KPAD / 4) return;
    int v  = idx * 4;
    int bc_ = v / KPAD;
    int l  = v - bc_ * KPAD;                           // multiple of 4
    float4 xv = make_float4(0.f, 0.f, 0.f, 0.f);
    if (l < LSP)                                       // LSP%4==0: uniform per vec
        xv = *(const float4*)&x[(size_t)bc_ * LSP + l];
    f16x4 hv;
    hv[0] = (_Float16)xv.x; hv[1] = (_Float16)xv.y;
    hv[2] = (_Float16)xv.z; hv[3] = (_Float16)xv.w;
    *(f16x4*)&xh[v] = hv;
}

// ---------------------------------------------------------------------------
// Kernel 2 (== R9's best-measured gram, 232 us): symmetric Gram tile (fp16
// MFMA) + LDS count-sketch scatter.  grid = 1088: batch = id&7 (one batch
// per XCD), pair = id>>3.  Scatter roofline: ds_add_f32 RMW throughput
// ~2.9 cyc/lane-op.  Flush: atomicAdd into one of 68 L2-resident part
// slots, rotated order (R11/R13: store-flush variants both lose ~18 us).
// ---------------------------------------------------------------------------
__device__ __forceinline__ void stage_tile(
    const _Float16* __restrict__ src, size_t rowbase_elems,
    unsigned short* lds_tile, int wv, int lane, int k0)
{
#pragma unroll
    for (int half = 0; half < 2; ++half) {
        int ch  = wv * 2 + half;                       // 0..7 chunk of 8KB tile
        int row = ch * 16 + (lane >> 2);
        int kg  = (lane & 3) ^ ((lane >> 3) & 3);      // XOR swizzle (row>>1)&3
        const _Float16* g = src + rowbase_elems
            + (size_t)row * KPAD + k0 + kg * 8;
        __builtin_amdgcn_global_load_lds(
            (__attribute__((address_space(1))) void*)g,
            (__attribute__((address_space(3))) void*)(lds_tile + ch * 512),
            16, 0, 0);
    }
}

__global__ __launch_bounds__(256, 3) void gram_scatter_kernel(
    const _Float16* __restrict__ xh,
    const int*   __restrict__ h1, const float* __restrict__ s1,
    const int*   __restrict__ h2, const float* __restrict__ s2,
    float* __restrict__ part)
{
    __shared__ __align__(16) unsigned short smA[128 * 32];   // 8 KB fp16 tile
    __shared__ __align__(16) unsigned short smB[128 * 32];   // 8 KB
    __shared__ __align__(16) float bins[DDIM];               // 32 KB
    __shared__ float4 metaA[128];                            // 2 KB

    const int tid  = threadIdx.x;
    const int lane = tid & 63;
    const int wv   = tid >> 6;
    const int b    = blockIdx.x & 7;       // batch in low bits -> one batch/XCD
    const int pidx = blockIdx.x >> 3;      // triangular pair index

    // Triangular decode: pidx in [0,136) -> (tM, tN), tM <= tN, row-major
    int tM = 0, tN = 0;
    {
        int i = pidx;
#pragma unroll 1
        for (int t = 0; t < NTILE; ++t) {
            int cnt = NTILE - t;
            if (i < cnt) { tM = t; tN = t + i; break; }
            i -= cnt;
        }
    }
    const bool diag = (tM == tN);

    for (int i = tid; i < DDIM; i += 256) bins[i] = 0.0f;
    // (first __syncthreads inside k-loop orders this before any scatter)

    const int wrow = (wv >> 1) * 64;    // wave's 64x64 subtile origin
    const int wcol = (wv & 1) * 64;

    const size_t rowbaseA = ((size_t)b * CH + (size_t)tM * 128) * KPAD;
    const size_t rowbaseB = ((size_t)b * CH + (size_t)tN * 128) * KPAD;

    const unsigned short* fragB = diag ? smA : smB;

    f32x4 acc[4][4];
    const f32x4 zv = {0.0f, 0.0f, 0.0f, 0.0f};
#pragma unroll
    for (int mi = 0; mi < 4; ++mi)
#pragma unroll
        for (int ni = 0; ni < 4; ++ni) acc[mi][ni] = zv;

    // fragment LDS offset: (row)*32 + fxor; XOR term is a per-lane constant
    const int fxor = (((lane >> 4) ^ ((lane >> 1) & 3)) << 3);
    const int rsel = lane & 15;

    for (int ks = 0; ks < KSTEPS; ++ks) {
        const int k0 = ks * 32;
        stage_tile(xh, rowbaseA, smA, wv, lane, k0);
        if (!diag) stage_tile(xh, rowbaseB, smB, wv, lane, k0);
        __syncthreads();

        f16x8 ah[4], bh[4];
#pragma unroll
        for (int i = 0; i < 4; ++i) {
            int offa = (wrow + i * 16 + rsel) * 32 + fxor;
            ah[i] = *(const f16x8*)&smA[offa];
            int offb = (wcol + i * 16 + rsel) * 32 + fxor;
            bh[i] = *(const f16x8*)&fragB[offb];
        }
#pragma unroll
        for (int mi = 0; mi < 4; ++mi)
#pragma unroll
            for (int ni = 0; ni < 4; ++ni)
                acc[mi][ni] = __builtin_amdgcn_mfma_f32_16x16x32_f16(ah[mi], bh[ni], acc[mi][ni], 0, 0, 0);
        __syncthreads();
    }

    // Stage scatter meta for this tile's 128 c1-rows into LDS.
    if (tid < 128) {
        int c1 = tM * 128 + tid;
        metaA[tid] = make_float4(s1[c1], __int_as_float(h1[c1]),
                                 s2[c1], __int_as_float(h2[c1]));
    }
    __syncthreads();

    // Scatter the 128x128 Gram tile into the LDS histogram.
    // C/D layout (m89-verified): col = lane&15, row = (lane>>4)*4 + reg
    // Off-diagonal pair: each entry contributes twice (G symmetric).
    const int c2b = tN * 128 + wcol + (lane & 15);
    const int rowsel = wrow + ((lane >> 4) << 2);
    int   h1c[4], h2c[4]; float s1c[4], s2c[4];
#pragma unroll
    for (int ni = 0; ni < 4; ++ni) {
        int c2 = c2b + ni * 16;
        h1c[ni] = h1[c2]; s1c[ni] = s1[c2];
        h2c[ni] = h2[c2]; s2c[ni] = s2[c2];
    }
#pragma unroll
    for (int mi = 0; mi < 4; ++mi) {
#pragma unroll
        for (int r = 0; r < 4; ++r) {
            float4 m = metaA[rowsel + mi * 16 + r];    // one ds_read_b128
            const float s1r = m.x, s2r = m.z;
            const int h1r = __float_as_int(m.y);
            const int h2r = __float_as_int(m.w);
#pragma unroll
            for (int ni = 0; ni < 4; ++ni) {
                float g = acc[mi][ni][r];
                FATOMIC(&bins[(h1r + h2c[ni]) & (DDIM - 1)], s1r * s2c[ni] * g);
                if (!diag)
                    FATOMIC(&bins[(h1c[ni] + h2r) & (DDIM - 1)], s1c[ni] * s2r * g);
            }
        }
    }

    __syncthreads();   // all scatters into bins complete

    // Flush to one of 68 part slots (2 blocks/slot), rotated start per block
    // to decontend cache lines.  Keeps part L2-resident for the head.
    float* pb = part + ((size_t)((pidx % NSLOT) * BATCH + b) * DDIM);
    const int rot = (blockIdx.x & 31) << 8;
    for (int i = tid; i < DDIM; i += 256) {
        int j = (i + rot) & (DDIM - 1);
        float v = bins[j];
        if (v != 0.0f) FATOMIC(&pb[j], v);
    }
}

// ---------------------------------------------------------------------------
// Kernel 3 (fused head, 256 blocks): block j owns d in [32j, 32j+32) for all
// batches; thread -> (b = tid>>5, dd = tid&31).  Sums the 68 part slots,
// writes unnormalized feat, accumulates norm[b] (tree+atomic) and
// unnormalized logits (W read exactly once across blocks; linearity:
// logit = (featU @ W)*inv + bias).  Ticket-gated last block rescales.
// ---------------------------------------------------------------------------
__global__ __launch_bounds__(256) void head_kernel(
    const float* __restrict__ part, const float* __restrict__ W,
    const float* __restrict__ bc, float* __restrict__ out,
    float* __restrict__ norm, int* __restrict__ done)
{
    const int j = blockIdx.x;
    const int tid = threadIdx.x;
    const int b  = tid >> 5;
    const int dd = tid & 31;
    const int d  = j * 32 + dd;

    __shared__ float fs[BATCH][32];    // unnormalized feat slice
    __shared__ float red[256];
    __shared__ int ticket;

    float s = 0.0f;
#pragma unroll 4
    for (int p = 0; p < NSLOT; ++p)
        s += part[((size_t)(p * BATCH + b)) * DDIM + d];
    float fu = copysignf(sqrtf(fabsf(s)), s);
    fs[b][dd] = fu;
    out[BATCH * NCLS + (size_t)b * DDIM + d] = fu;     // unnormalized feat
    red[tid] = fabsf(s);                               // sum|y| == sum featU^2
    __syncthreads();

    // norm partial: reduce each 32-thread (single-batch) group
#pragma unroll
    for (int st = 16; st > 0; st >>= 1) {
        if ((tid & 31) < st) red[tid] += red[tid + st];
        __syncthreads();
    }
    if ((tid & 31) == 0) FATOMIC(&norm[b], red[tid]);

    // GEMV partial: lanes < NCLS, coalesced W rows, 8 batches per lane
    if (tid < NCLS) {
        float a[BATCH];
#pragma unroll
        for (int bb = 0; bb < BATCH; ++bb) a[bb] = 0.0f;
#pragma unroll 4
        for (int k = 0; k < 32; ++k) {
            float w = W[(size_t)(j * 32 + k) * NCLS + tid];
#pragma unroll
            for (int bb = 0; bb < BATCH; ++bb) a[bb] += fs[bb][k] * w;
        }
#pragma unroll
        for (int bb = 0; bb < BATCH; ++bb)
            FATOMIC(&out[bb * NCLS + tid], a[bb]);     // logit_u (zero-seeded)
    }

    // --- ticket-gated last-block rescale (pattern verified R13) ---
    __threadfence();
    __syncthreads();
    if (tid == 0) ticket = atomicAdd(done, 1);
    __syncthreads();
    if (ticket == 255) {
        __threadfence();
        __shared__ float inv[BATCH];
        if (tid < BATCH) inv[tid] = 1.0f / fmaxf(sqrtf(norm[tid]), 1e-12f);
        __syncthreads();
        for (int i = tid; i < BATCH * DDIM; i += 256) {
            int bb = i >> 13;                          // i / DDIM
            out[BATCH * NCLS + i] *= inv[bb];
        }
        for (int i = tid; i < BATCH * NCLS; i += 256) {
            int bb = i / NCLS, n = i - bb * NCLS;
            out[i] = out[i] * inv[bb] + bc[n];
        }
    }
}

// ---------------------------------------------------------------------------
extern "C" void kernel_launch(void* const* d_in, const int* in_sizes, int n_in,
                              void* d_out, int out_size, void* d_ws, size_t ws_size,
                              hipStream_t stream)
{
    const float* x  = (const float*)d_in[0];
    const float* s1 = (const float*)d_in[1];
    const float* s2 = (const float*)d_in[2];
    const float* W  = (const float*)d_in[3];
    const float* bc = (const float*)d_in[4];
    const int*   h1 = (const int*)d_in[5];
    const int*   h2 = (const int*)d_in[6];
    float* out = (float*)d_out;

    // ws layout: part (17.8MB) | norm (128B) | done (128B) | xh (26.2MB)
    char* ws = (char*)d_ws;
    float* part = (float*)ws;
    const size_t partbytes = (size_t)NSLOT * BATCH * DDIM * sizeof(float);
    float* norm = (float*)(ws + partbytes);
    int*   done = (int*)(ws + partbytes + 128);
    _Float16* xh = (_Float16*)(ws + partbytes + 256);

    split_kernel<<<(BATCH * CH * KPAD / 4 + 255) / 256, 256, 0, stream>>>(
        x, xh, part, norm, done, out);

    gram_scatter_kernel<<<NPAIR * BATCH, 256, 0, stream>>>(
        xh, h1, s1, h2, s2, part);

    head_kernel<<<256, 256, 0, stream>>>(part, W, bc, out, norm, done);
}